// Round 4
// baseline (6477.448 us; speedup 1.0000x reference)
//
#include <hip/hip_runtime.h>
#include <stdint.h>

#define T_LEN 1024
#define BATCH 32
#define DIN   512
#define HID   512
#define G3    1536          // 3*HID
#define ROWS  (T_LEN*BATCH) // 32768
#define NSL   8             // h-slices (blocks) per direction
#define MBOX_DEPTH 4        // tagged mailbox ring depth (slot = t & 3)

typedef short bf16x8 __attribute__((ext_vector_type(8)));
typedef float f32x4  __attribute__((ext_vector_type(4)));
typedef uint32_t u32x4 __attribute__((ext_vector_type(4)));
typedef uint32_t u32x2 __attribute__((ext_vector_type(2)));

__device__ __forceinline__ unsigned short f2bf(float f) {
  union { float f; uint32_t u; } v; v.f = f;
  uint32_t u = v.u;
  return (unsigned short)((u + 0x7fffu + ((u >> 16) & 1u)) >> 16);  // RNE
}
__device__ __forceinline__ float bf2f(unsigned short h) {
  union { uint32_t u; float f; } v; v.u = ((uint32_t)h) << 16; return v.f;
}
__device__ __forceinline__ float sigm(float x)   { return 1.f / (1.f + __expf(-x)); }
__device__ __forceinline__ float tanh_f(float x) { return 2.f / (1.f + __expf(-2.f * x)) - 1.f; }

// ---------------- zero init (bn stats only; mailbox needs none: tags gate) ----------------
__global__ void zero_init(float* stats) {
  int i = blockIdx.x * 256 + threadIdx.x;
  if (i < 2 * G3) stats[i] = 0.f;
}

// ---------------- f32 -> bf16 convert ----------------
__global__ void convert_bf16(const float* __restrict__ src, unsigned short* __restrict__ dst, int n4) {
  int i = blockIdx.x * 256 + threadIdx.x;
  if (i < n4) {
    float4 v = ((const float4*)src)[i];
    ushort4 o;
    o.x = f2bf(v.x); o.y = f2bf(v.y); o.z = f2bf(v.z); o.w = f2bf(v.w);
    ((ushort4*)dst)[i] = o;
  }
}

// ---------------- P = x @ Wx^T  (bf16 in, bf16 out, fp32 acc) ----------------
__global__ __launch_bounds__(256) void gemm_proj(const unsigned short* __restrict__ xb,
                                                 const unsigned short* __restrict__ wxb,
                                                 unsigned short* __restrict__ P) {
  int w = threadIdx.x >> 6;
  int l = threadIdx.x & 63;
  int mi = w >> 1, ni = w & 1;
  int row_base = blockIdx.x * 64 + mi * 32;
  int col_base = blockIdx.y * 64 + ni * 32;
  int lr = l & 15, lk8 = (l >> 4) * 8;
  f32x4 acc00 = {0,0,0,0}, acc01 = {0,0,0,0}, acc10 = {0,0,0,0}, acc11 = {0,0,0,0};
  #pragma unroll 4
  for (int kk = 0; kk < 16; ++kk) {
    int k0 = kk * 32 + lk8;
    bf16x8 a0 = *(const bf16x8*)(xb  + (size_t)(row_base + lr) * DIN + k0);
    bf16x8 a1 = *(const bf16x8*)(xb  + (size_t)(row_base + 16 + lr) * DIN + k0);
    bf16x8 b0 = *(const bf16x8*)(wxb + (size_t)(col_base + lr) * DIN + k0);
    bf16x8 b1 = *(const bf16x8*)(wxb + (size_t)(col_base + 16 + lr) * DIN + k0);
    acc00 = __builtin_amdgcn_mfma_f32_16x16x32_bf16(a0, b0, acc00, 0, 0, 0);
    acc01 = __builtin_amdgcn_mfma_f32_16x16x32_bf16(a0, b1, acc01, 0, 0, 0);
    acc10 = __builtin_amdgcn_mfma_f32_16x16x32_bf16(a1, b0, acc10, 0, 0, 0);
    acc11 = __builtin_amdgcn_mfma_f32_16x16x32_bf16(a1, b1, acc11, 0, 0, 0);
  }
  int rrow = (l >> 4) * 4;
  #pragma unroll
  for (int r = 0; r < 4; ++r) {
    P[(size_t)(row_base +      rrow + r) * G3 + col_base +      lr] = f2bf(acc00[r]);
    P[(size_t)(row_base +      rrow + r) * G3 + col_base + 16 + lr] = f2bf(acc01[r]);
    P[(size_t)(row_base + 16 + rrow + r) * G3 + col_base +      lr] = f2bf(acc10[r]);
    P[(size_t)(row_base + 16 + rrow + r) * G3 + col_base + 16 + lr] = f2bf(acc11[r]);
  }
}

// ---------------- per-channel sums over rows ----------------
__global__ void bn_stats(const unsigned short* __restrict__ P, float* __restrict__ stats) {
  int col = blockIdx.x * 256 + threadIdx.x;   // grid.x = 6  -> 1536 cols
  int r0  = blockIdx.y * 512;                 // grid.y = 64 -> 32768 rows
  float s = 0.f, q = 0.f;
  for (int r = 0; r < 512; ++r) {
    float v = bf2f(P[(size_t)(r0 + r) * G3 + col]);
    s += v; q += v * v;
  }
  atomicAdd(&stats[col], s);
  atomicAdd(&stats[G3 + col], q);
}

// ---------------- fold BN into scale/shift ----------------
__global__ void bn_final(const float* __restrict__ stats, const float* __restrict__ gamma,
                         const float* __restrict__ beta, float* __restrict__ params) {
  int c = blockIdx.x * 256 + threadIdx.x;
  if (c >= G3) return;
  float mean = stats[c] * (1.f / ROWS);
  float var  = stats[G3 + c] * (1.f / ROWS) - mean * mean;
  float sc = gamma[c] * rsqrtf(var + 1e-5f);
  params[c] = sc;
  params[G3 + c] = beta[c] - mean * sc;
}

// ---------------- the bidirectional GRU scan ----------------
// 16 blocks: [0,8) fwd, [8,16) bwd. Block owns h-cols [s*64, s*64+64).
// SINGLE-HOP sync: h published as tagged dwords ((t+1)<<16 | bf16) into a
// depth-4 mailbox ring, write-through sc0|sc1. Consumers poll the data
// dwords directly (tag-valid => value-valid; dword stores are atomic).
// No flags, no drains, no fences on the critical path.
__global__ __launch_bounds__(256, 1) void scan_kernel(
    const unsigned short* __restrict__ P, const float* __restrict__ params,
    const unsigned short* __restrict__ whf, const unsigned short* __restrict__ whb,
    unsigned short* __restrict__ histf, unsigned short* __restrict__ histb,
    uint32_t* __restrict__ mboxf, uint32_t* __restrict__ mboxb) {
  int blk = blockIdx.x;
  int d = blk >> 3;          // direction
  int s = blk & 7;           // slice
  int j0 = s * 64;           // first owned h column
  int tid = threadIdx.x;
  int w = tid >> 6, l = tid & 63;
  int lr = l & 15, lk8 = (l >> 4) * 8;

  const unsigned short* wh = d ? whb : whf;
  unsigned short* myhist = d ? histb : histf;
  uint32_t* mybox = d ? mboxb : mboxf;

  // B fragments: wave w owns hp-col tiles i = w*3+q (q=0..2);
  // tile i -> gate g = i>>2, sub n = i&3, cols cb = g*512 + j0 + n*16.
  bf16x8 bfrag[3][16];
  #pragma unroll
  for (int q = 0; q < 3; ++q) {
    int i = w * 3 + q;
    int cb = (i >> 2) * HID + j0 + (i & 3) * 16;
    const unsigned short* wrow = wh + (size_t)(cb + lr) * HID;
    #pragma unroll
    for (int kk = 0; kk < 16; ++kk)
      bfrag[q][kk] = *(const bf16x8*)(wrow + kk * 32 + lk8);
  }

  __shared__ __align__(16) char hlds[BATCH * HID * 2];  // 32 KB XOR-swizzled packed h_prev
  __shared__ float hp[3][BATCH][66];                    // padded vs bank conflicts

  // epilogue mapping: thread -> column PAIR jc0 = j0 + 2*(tid&31), batches (tid>>5)+i*8
  int jp = tid & 31;
  int jc0 = j0 + jp * 2;
  float scr[2], shr[2], scz[2], shz[2], scn[2], shn[2];
  #pragma unroll
  for (int u = 0; u < 2; ++u) {
    int c = jc0 + u;
    scr[u] = params[c];           shr[u] = params[G3 + c];
    scz[u] = params[HID + c];     shz[u] = params[G3 + HID + c];
    scn[u] = params[2 * HID + c]; shn[u] = params[G3 + 2 * HID + c];
  }

  for (int t = 0; t < T_LEN; ++t) {
    int time = d ? (T_LEN - 1 - t) : t;

    // ---- prefetch this step's x-projection values (h-independent) ----
    uint32_t pr[4], pz[4], pn[4];
    #pragma unroll
    for (int i = 0; i < 4; ++i) {
      int b = (tid >> 5) + i * 8;
      const unsigned short* prow = P + (size_t)(time * BATCH + b) * G3 + jc0;
      pr[i] = *(const uint32_t*)(prow);
      pz[i] = *(const uint32_t*)(prow + HID);
      pn[i] = *(const uint32_t*)(prow + 2 * HID);
    }

    // ---- poll tagged mailbox for h_{t-1}; stage valid chunks to LDS ----
    if (t > 0) {
      uint32_t expect = ((uint32_t)t) << 16;               // tag of h_{t-1}
      const uint32_t* mb = mybox + (size_t)((t - 1) & (MBOX_DEPTH - 1)) * (BATCH * HID);
      u32x4 hv[16];
      uint32_t pend = 0xffffu;   // bit per 4-dword chunk
      int guard = 0;
      do {
        #pragma unroll
        for (int i = 0; i < 16; ++i) {
          if (pend & (1u << i)) {
            const uint32_t* a = mb + (size_t)(tid + i * 256) * 4;
            asm volatile("global_load_dwordx4 %0, %1, off sc0 sc1"
                         : "=v"(hv[i]) : "v"(a) : "memory");
          }
        }
        asm volatile("s_waitcnt vmcnt(0)" ::: "memory");
        __builtin_amdgcn_sched_barrier(0);
        #pragma unroll
        for (int i = 0; i < 16; ++i) {
          if (pend & (1u << i)) {
            uint32_t diff = ((hv[i].x ^ expect) | (hv[i].y ^ expect) |
                             (hv[i].z ^ expect) | (hv[i].w ^ expect)) & 0xffff0000u;
            if (diff == 0) {
              int c = tid + i * 256;               // chunk = 4 values
              int row = c >> 7;                    // 128 chunks per batch-row
              int colb = (c & 127) * 8;            // packed byte offset in row
              u32x2 pk;
              pk.x = (hv[i].x & 0xffffu) | (hv[i].y << 16);
              pk.y = (hv[i].z & 0xffffu) | (hv[i].w << 16);
              *(u32x2*)(hlds + ((row * 1024 + colb) ^ ((row & 7) << 4))) = pk;
              pend &= ~(1u << i);
            }
          }
        }
        if (pend) { if (++guard > (1 << 13)) break; }   // bailout beats a hang
      } while (pend);
    } else {
      u32x2 z = {0, 0};
      #pragma unroll
      for (int i = 0; i < 16; ++i) {
        int c = tid + i * 256;
        int row = c >> 7;
        int colb = (c & 127) * 8;
        *(u32x2*)(hlds + ((row * 1024 + colb) ^ ((row & 7) << 4))) = z;
      }
    }
    __syncthreads();

    // ---- hp = h_prev @ Wh_slice^T : M=32, N=48/wave, K=512 ----
    f32x4 acc[2][3] = {};
    #pragma unroll
    for (int kk = 0; kk < 16; ++kk) {
      int cbase = kk * 64 + lk8 * 2;
      int sw = (lr & 7) << 4;               // (lr+16)&7 == lr&7
      bf16x8 a0 = *(const bf16x8*)(hlds + ((lr * 1024 + cbase) ^ sw));
      bf16x8 a1 = *(const bf16x8*)(hlds + (((lr + 16) * 1024 + cbase) ^ sw));
      #pragma unroll
      for (int q = 0; q < 3; ++q) {
        acc[0][q] = __builtin_amdgcn_mfma_f32_16x16x32_bf16(a0, bfrag[q][kk], acc[0][q], 0, 0, 0);
        acc[1][q] = __builtin_amdgcn_mfma_f32_16x16x32_bf16(a1, bfrag[q][kk], acc[1][q], 0, 0, 0);
      }
    }
    // D layout: row = (l>>4)*4 + r, col = l&15
    #pragma unroll
    for (int q = 0; q < 3; ++q) {
      int i = w * 3 + q;
      int g = i >> 2, ncol = (i & 3) * 16 + lr;
      #pragma unroll
      for (int m = 0; m < 2; ++m) {
        int rrow = m * 16 + (l >> 4) * 4;
        #pragma unroll
        for (int r = 0; r < 4; ++r) hp[g][rrow + r][ncol] = acc[m][q][r];
      }
    }
    __syncthreads();

    // ---- gates + h update: 2 cols x 4 batches per thread ----
    unsigned short* hout = myhist + (size_t)t * BATCH * HID;
    uint32_t* mslot = mybox + (size_t)(t & (MBOX_DEPTH - 1)) * (BATCH * HID);
    uint32_t tagw = ((uint32_t)(t + 1)) << 16;
    #pragma unroll
    for (int i = 0; i < 4; ++i) {
      int b = (tid >> 5) + i * 8;
      float2 rp2 = *(const float2*)&hp[0][b][2 * jp];
      float2 zp2 = *(const float2*)&hp[1][b][2 * jp];
      float2 np2 = *(const float2*)&hp[2][b][2 * jp];
      uint32_t hpair = *(const uint32_t*)(hlds + ((b * 1024 + jc0 * 2) ^ ((b & 7) << 4)));
      uint32_t o = 0;
      #pragma unroll
      for (int u = 0; u < 2; ++u) {
        float xrv = bf2f((unsigned short)((u ? (pr[i] >> 16) : pr[i]) & 0xffff));
        float xzv = bf2f((unsigned short)((u ? (pz[i] >> 16) : pz[i]) & 0xffff));
        float xnv = bf2f((unsigned short)((u ? (pn[i] >> 16) : pn[i]) & 0xffff));
        float rpv = u ? rp2.y : rp2.x;
        float zpv = u ? zp2.y : zp2.x;
        float npv = u ? np2.y : np2.x;
        float rv = sigm(fmaf(xrv, scr[u], shr[u]) + rpv);
        float zv = sigm(fmaf(xzv, scz[u], shz[u]) + zpv);
        float nv = tanh_f(fmaf(xnv, scn[u], shn[u]) + rv * npv);
        float hold = bf2f((unsigned short)((u ? (hpair >> 16) : hpair) & 0xffff));
        unsigned short ho = f2bf((1.f - zv) * hold + zv * nv);
        o |= ((uint32_t)ho) << (16 * u);
      }
      // plain history for final_add (cached; read after kernel boundary)
      *(uint32_t*)(hout + (size_t)b * HID + jc0) = o;
      // tagged mailbox publish (write-through, single-hop sync)
      u32x2 tv;
      tv.x = tagw | (o & 0xffffu);
      tv.y = tagw | (o >> 16);
      uint32_t* maddr = mslot + (size_t)b * HID + jc0;
      asm volatile("global_store_dwordx2 %0, %1, off sc0 sc1"
                   :: "v"(maddr), "v"(tv) : "memory");
    }
    __syncthreads();   // protect hlds/hp against next iteration's overwrite
  }
}

// ---------------- out[t] = fwd[t] + bwd[T-1-t] ----------------
__global__ void final_add(const unsigned short* __restrict__ histf,
                          const unsigned short* __restrict__ histb,
                          float* __restrict__ out) {
  size_t i4 = (size_t)blockIdx.x * 256 + threadIdx.x;
  size_t e = i4 * 4;
  int t = (int)(e / (BATCH * HID));
  size_t rem = e % (BATCH * HID);
  ushort4 vf = *(const ushort4*)(histf + e);
  ushort4 vb = *(const ushort4*)(histb + (size_t)(T_LEN - 1 - t) * BATCH * HID + rem);
  float4 o;
  o.x = bf2f(vf.x) + bf2f(vb.x);
  o.y = bf2f(vf.y) + bf2f(vb.y);
  o.z = bf2f(vf.z) + bf2f(vb.z);
  o.w = bf2f(vf.w) + bf2f(vb.w);
  *(float4*)(out + e) = o;
}

extern "C" void kernel_launch(void* const* d_in, const int* in_sizes, int n_in,
                              void* d_out, int out_size, void* d_ws, size_t ws_size,
                              hipStream_t stream) {
  const float* x     = (const float*)d_in[0];
  const float* Wx    = (const float*)d_in[1];
  const float* Whf   = (const float*)d_in[2];
  const float* Whb   = (const float*)d_in[3];
  const float* gamma = (const float*)d_in[4];
  const float* beta  = (const float*)d_in[5];
  float* out = (float*)d_out;

  char* ws = (char*)d_ws;
  size_t off = 0;
  auto alloc = [&](size_t bytes) {
    char* p = ws + off;
    off += (bytes + 255) & ~(size_t)255;
    return p;
  };
  unsigned short* xb    = (unsigned short*)alloc((size_t)ROWS * DIN * 2);
  unsigned short* wxb   = (unsigned short*)alloc((size_t)G3 * DIN * 2);
  unsigned short* whfb  = (unsigned short*)alloc((size_t)G3 * HID * 2);
  unsigned short* whbb  = (unsigned short*)alloc((size_t)G3 * HID * 2);
  unsigned short* P     = (unsigned short*)alloc((size_t)ROWS * G3 * 2);
  float* stats          = (float*)alloc(2 * G3 * 4);
  float* params         = (float*)alloc(2 * G3 * 4);
  unsigned short* histf = (unsigned short*)alloc((size_t)T_LEN * BATCH * HID * 2);
  unsigned short* histb = (unsigned short*)alloc((size_t)T_LEN * BATCH * HID * 2);
  uint32_t* mboxf       = (uint32_t*)alloc((size_t)MBOX_DEPTH * BATCH * HID * 4);
  uint32_t* mboxb       = (uint32_t*)alloc((size_t)MBOX_DEPTH * BATCH * HID * 4);

  hipLaunchKernelGGL(zero_init, dim3(12), dim3(256), 0, stream, stats);
  hipLaunchKernelGGL(convert_bf16, dim3(16384), dim3(256), 0, stream, x, xb, ROWS * DIN / 4);
  hipLaunchKernelGGL(convert_bf16, dim3(768), dim3(256), 0, stream, Wx, wxb, G3 * DIN / 4);
  hipLaunchKernelGGL(convert_bf16, dim3(768), dim3(256), 0, stream, Whf, whfb, G3 * HID / 4);
  hipLaunchKernelGGL(convert_bf16, dim3(768), dim3(256), 0, stream, Whb, whbb, G3 * HID / 4);
  hipLaunchKernelGGL(gemm_proj, dim3(512, 24), dim3(256), 0, stream, xb, wxb, P);
  hipLaunchKernelGGL(bn_stats, dim3(6, 64), dim3(256), 0, stream, P, stats);
  hipLaunchKernelGGL(bn_final, dim3(6), dim3(256), 0, stream, stats, gamma, beta, params);
  hipLaunchKernelGGL(scan_kernel, dim3(16), dim3(256), 0, stream,
                     P, params, whfb, whbb, histf, histb, mboxf, mboxb);
  hipLaunchKernelGGL(final_add, dim3(16384), dim3(256), 0, stream, histf, histb, out);
}